// Round 1
// baseline (459.337 us; speedup 1.0000x reference)
//
#include <hip/hip_runtime.h>

#define G      1024
#define NNODES 65536
#define NEDGES 262144
#define D      256
#define DIN    768
#define DHID   512
#define DOUT   256
#define CW     512            // collected row width: [edge_agg | node_agg]

#define AGG_BLOCKS 1024       // x 4 waves = 4096 waves
#define EROWS      64         // edge rows per wave  (4096*64 = 262144)
#define NROWS      16         // node rows per wave  (4096*16 = 65536)

__device__ __forceinline__ void flush_acc(float* __restrict__ dst, int cur, int col,
                                          float4& acc) {
    float* p = dst + (size_t)cur * CW + col;
    atomicAdd(p + 0, acc.x); atomicAdd(p + 1, acc.y);
    atomicAdd(p + 2, acc.z); atomicAdd(p + 3, acc.w);
    acc.x = acc.y = acc.z = acc.w = 0.f;
}

__device__ __forceinline__ void row_step(int id, const float4 v, int& cur, float4& acc,
                                         float* __restrict__ dst, int col) {
    if (id != cur) { flush_acc(dst, cur, col, acc); cur = id; }
    acc.x += v.x; acc.y += v.y; acc.z += v.z; acc.w += v.w;
}

// Load one 8-row group: 8 KiB contiguous (rows r..r+7, lane covers 16 B of each
// row) + the 8 ids. All 10 loads are independent — issued as one burst.
__device__ __forceinline__ void load_group(const float4* __restrict__ src,
                                           const int* __restrict__ ids, int r, int lane,
                                           float4 v[8], int4& i0, int4& i1) {
    const float4* p = src + (size_t)r * (D / 4) + lane;
#pragma unroll
    for (int j = 0; j < 8; ++j) v[j] = p[j * (D / 4)];
    i0 = *(const int4*)&ids[r];
    i1 = *(const int4*)&ids[r + 4];
}

__device__ __forceinline__ void proc_group(const float4 v[8], int4 i0, int4 i1,
                                           int& cur, float4& acc,
                                           float* __restrict__ dst, int col) {
    if (i0.x == cur && i1.w == cur) {   // whole group inside current run (common)
        acc.x += ((v[0].x + v[1].x) + (v[2].x + v[3].x)) + ((v[4].x + v[5].x) + (v[6].x + v[7].x));
        acc.y += ((v[0].y + v[1].y) + (v[2].y + v[3].y)) + ((v[4].y + v[5].y) + (v[6].y + v[7].y));
        acc.z += ((v[0].z + v[1].z) + (v[2].z + v[3].z)) + ((v[4].z + v[5].z) + (v[6].z + v[7].z));
        acc.w += ((v[0].w + v[1].w) + (v[2].w + v[3].w)) + ((v[4].w + v[5].w) + (v[6].w + v[7].w));
    } else {                            // run boundary inside the group
        row_step(i0.x, v[0], cur, acc, dst, col);
        row_step(i0.y, v[1], cur, acc, dst, col);
        row_step(i0.z, v[2], cur, acc, dst, col);
        row_step(i0.w, v[3], cur, acc, dst, col);
        row_step(i1.x, v[4], cur, acc, dst, col);
        row_step(i1.y, v[5], cur, acc, dst, col);
        row_step(i1.z, v[6], cur, acc, dst, col);
        row_step(i1.w, v[7], cur, acc, dst, col);
    }
}

// Sorted-segment sum with register ping-pong pipeline: group k+1's loads are
// issued before group k's accumulate, so ~8-16 KiB stays in flight per wave at
// all times (no vmcnt(0) drain in steady state). Flush via atomicAdd only at
// run boundaries (~1.25 per wave on average).
__device__ __forceinline__ void seg_sum_pipelined(
        const float4* __restrict__ src, const int* __restrict__ ids,
        float* __restrict__ dst, int col, int r, int ngroups, int lane) {
    float4 va[8], vb[8];
    int4 ia0, ia1, ib0, ib1;
    float4 acc = {0.f, 0.f, 0.f, 0.f};
    int cur = ids[r];

    load_group(src, ids, r, lane, va, ia0, ia1);
    for (int gpair = 0; gpair < ngroups / 2 - 1; ++gpair) {
        load_group(src, ids, r + 8, lane, vb, ib0, ib1);
        proc_group(va, ia0, ia1, cur, acc, dst, col);
        r += 8;
        load_group(src, ids, r + 8, lane, va, ia0, ia1);
        proc_group(vb, ib0, ib1, cur, acc, dst, col);
        r += 8;
    }
    load_group(src, ids, r + 8, lane, vb, ib0, ib1);
    proc_group(va, ia0, ia1, cur, acc, dst, col);
    proc_group(vb, ib0, ib1, cur, acc, dst, col);
    flush_acc(dst, cur, col, acc);
}

// 1024 blocks x 256 thr, launch_bounds(256,4) -> 16 waves/CU, no LDS.
// Wave W: edge rows [W*64, +64) then node rows [W*16, +16), contiguous.
// BW-bound by model (~320 MB @ ~6.3 TB/s ≈ 55 µs) — unchanged this round.
__global__ __launch_bounds__(256, 4) void fused_agg(
        const float4* __restrict__ nodes,
        const float4* __restrict__ edges,
        const int* __restrict__ nids,
        const int* __restrict__ eids,
        float* __restrict__ collected) {
    const int lane = threadIdx.x & 63;
    const int wave = threadIdx.x >> 6;
    const int W    = blockIdx.x * 4 + wave;         // 0..4095

    seg_sum_pipelined(edges, eids, collected, lane * 4,       W * EROWS, EROWS / 8, lane);
    seg_sum_pipelined(nodes, nids, collected, D + lane * 4,   W * NROWS, NROWS / 8, lane);
}

// fp32 GEMM: C[M,N]=act(A@B+bias), tile 32x64, TK=32, **512 thr** (8 waves =
// 2 waves/SIMD with grid=1 block/CU — was 256 thr = 1 wave/SIMD, fully
// exposing ds_read (~120cy) and the per-tile global-prefetch wait (~900cy miss
// vs ~640cy compute)). Micro 1x4 per thread, k-major A in LDS (+1 pad, <=2-way
// banks), reg->LDS double buffer, one barrier per K-tile. A split across two
// sources: cols [0,asplit) from A1 (stride s1), cols [asplit,K) from A2
// (stride s2) — lets GEMM1 read globals_ in place.
__global__ __launch_bounds__(512) void gemm_bias_act(
        const float* __restrict__ A1, const float* __restrict__ A2,
        const float* __restrict__ B,
        const float* __restrict__ bias, float* __restrict__ C,
        int N, int K, int asplit, int s1, int s2, int relu) {
    __shared__ float At[2][32][33];
    __shared__ __align__(16) float Bs[2][32][64];

    const int tid = threadIdx.x;
    const int tx = tid & 15;          // output col group (float4): cols tx*4..+3
    const int ty = tid >> 4;          // output row 0..31
    const int m0 = blockIdx.y * 32;
    const int n0 = blockIdx.x * 64;

    const int ar = ty;                // A-tile row (m), 0..31
    const int ac = tx * 2;            // A-tile k-offset (float2), 0..30
    const int br = ty;                // B-tile row (k), 0..31
    const int bc = tx * 4;            // B-tile col (float4), 0..60

    const int arow = m0 + ar;
    const float* Bptr = B + (size_t)br * N + n0 + bc;

    auto loadA = [&](int kc) -> float2 {
        return (kc < asplit) ? *(const float2*)&A1[(size_t)arow * s1 + kc + ac]
                             : *(const float2*)&A2[(size_t)arow * s2 + (kc - asplit) + ac];
    };

    {
        const float2 a2 = loadA(0);
        const float4 b4 = *(const float4*)Bptr;
        At[0][ac + 0][ar] = a2.x;
        At[0][ac + 1][ar] = a2.y;
        *(float4*)&Bs[0][br][bc] = b4;
    }
    __syncthreads();

    float4 acc = {0.f, 0.f, 0.f, 0.f};
    int buf = 0;

    for (int kt = 0; kt < K; kt += 32) {
        const bool has_next = (kt + 32) < K;
        float2 na; float4 nb;
        if (has_next) {
            na = loadA(kt + 32);
            nb = *(const float4*)(Bptr + (size_t)(kt + 32) * N);
        }
#pragma unroll
        for (int k = 0; k < 32; ++k) {
            const float a  = At[buf][k][ty];                    // 4-addr broadcast
            const float4 bv = *(const float4*)&Bs[buf][k][tx * 4];  // b128, 2-way
            acc.x += a * bv.x; acc.y += a * bv.y;
            acc.z += a * bv.z; acc.w += a * bv.w;
        }
        if (has_next) {
            const int nxt = buf ^ 1;
            At[nxt][ac + 0][ar] = na.x;
            At[nxt][ac + 1][ar] = na.y;
            *(float4*)&Bs[nxt][br][bc] = nb;
            __syncthreads();
            buf = nxt;
        }
    }

    const int col = n0 + tx * 4;
    const int row = m0 + ty;
    const float4 bv = *(const float4*)&bias[col];
    float4 o;
    o.x = acc.x + bv.x; o.y = acc.y + bv.y;
    o.z = acc.z + bv.z; o.w = acc.w + bv.w;
    if (relu) {
        o.x = fmaxf(o.x, 0.f); o.y = fmaxf(o.y, 0.f);
        o.z = fmaxf(o.z, 0.f); o.w = fmaxf(o.w, 0.f);
    }
    *(float4*)&C[(size_t)row * N + col] = o;
}

extern "C" void kernel_launch(void* const* d_in, const int* in_sizes, int n_in,
                              void* d_out, int out_size, void* d_ws, size_t ws_size,
                              hipStream_t stream) {
    const float* nodes    = (const float*)d_in[0];
    const float* edges    = (const float*)d_in[1];
    const float* globals_ = (const float*)d_in[2];
    const int*   nids     = (const int*)d_in[3];
    const int*   eids     = (const int*)d_in[4];
    const float* W1       = (const float*)d_in[5];
    const float* b1       = (const float*)d_in[6];
    const float* W2       = (const float*)d_in[7];
    const float* b2       = (const float*)d_in[8];
    float* out = (float*)d_out;

    float* collected = (float*)d_ws;                 // [G, 512] (2 MB), atomic-accumulated
    float* h         = collected + (size_t)G * CW;   // [G, DHID] (2 MB), fully written

    // zero the accumulator buffer (ws re-poisoned 0xAA before every launch)
    hipMemsetAsync(collected, 0, (size_t)G * CW * sizeof(float), stream);

    fused_agg<<<AGG_BLOCKS, 256, 0, stream>>>(
        (const float4*)nodes, (const float4*)edges, nids, eids, collected);

    // GEMM1: A = [collected | globals_] (K=768 split at 512), relu
    gemm_bias_act<<<dim3(DHID / 64, G / 32), 512, 0, stream>>>(
        collected, globals_, W1, b1, h, DHID, DIN, CW, CW, D, 1);

    // GEMM2: A = h (K=512, no split), no relu
    gemm_bias_act<<<dim3(DOUT / 64, G / 32), 512, 0, stream>>>(
        h, h, W2, b2, out, DOUT, DHID, DHID, DHID, DHID, 0);
}